// Round 3
// baseline (415.052 us; speedup 1.0000x reference)
//
#include <hip/hip_runtime.h>
#include <stdint.h>

typedef _Float16 half8 __attribute__((ext_vector_type(8)));
typedef float    f32x4 __attribute__((ext_vector_type(4)));

static __device__ __forceinline__ void async_cp16(const void* g, void* l) {
  __builtin_amdgcn_global_load_lds(
      (const __attribute__((address_space(1))) uint32_t*)g,
      (__attribute__((address_space(3))) uint32_t*)l,
      16, 0, 0);
}

// ---------------------------------------------------------------------------
// Weight packing into MFMA-fragment order (1 fragment = 64 lanes x 16B = 1KB).
// Fragment: lane -> n=(lane&15), k-sub=(lane>>4)*8+e.
// pw1: 28 ks x 8 nt (K 784 padded->896, conv folded).  f = gks*8+nt
// pw2: g(0..3) x 4 ks x 8 nt                           f = g*32+ks*8+nt
// pw3: c(0..7)=(g,half) x 4 ks x 8 nt                  f = c*32+ks*8+nt
// pw4: 8 ks x 1 nt (N 10 padded->16)
// ---------------------------------------------------------------------------
__global__ void pack_all(const float* __restrict__ w1, const float* __restrict__ wc,
                         const float* __restrict__ w2, const float* __restrict__ w3,
                         const float* __restrict__ w4,
                         _Float16* __restrict__ pw1, _Float16* __restrict__ pw2,
                         _Float16* __restrict__ pw3, _Float16* __restrict__ pw4)
{
  int idx = (int)blockIdx.x * 256 + (int)threadIdx.x;

  if (idx < 114688) {           // L1: 28 ks x 8 nt fragments
    const int e = idx & 7, lane = (idx >> 3) & 63, f = idx >> 9;
    const int nt = f & 7, gks = f >> 3;
    const int n = nt * 16 + (lane & 15);
    const int k = gks * 32 + ((lane >> 4) << 3) + e;
    float val = 0.0f;
    if (k < 784) {
      const int pr = k / 28, pc = k % 28;
      #pragma unroll
      for (int i = 0; i < 3; ++i)
        #pragma unroll
        for (int j = 0; j < 3; ++j) {
          const int orow = pr - i, ocol = pc - j;
          if (orow >= 0 && orow < 26 && ocol >= 0 && ocol < 26)
            val += wc[i * 3 + j] * w1[n * 676 + orow * 26 + ocol];
        }
    }
    pw1[idx] = (_Float16)val;
    return;
  }
  idx -= 114688;
  if (idx < 65536) {            // L2
    const int e = idx & 7, lane = (idx >> 3) & 63, f = idx >> 9;
    const int nt = f & 7, ks = (f >> 3) & 3, g = f >> 5;
    const int n = g * 128 + nt * 16 + (lane & 15);
    const int k = ks * 32 + ((lane >> 4) << 3) + e;
    pw2[idx] = (_Float16)w2[n * 128 + k];
    return;
  }
  idx -= 65536;
  if (idx < 131072) {           // L3
    const int e = idx & 7, lane = (idx >> 3) & 63, f = idx >> 9;
    const int nt = f & 7, ks = (f >> 3) & 3, c = f >> 5;
    const int n = ((c & 1) * 8 + nt) * 16 + (lane & 15);
    const int k = ((c >> 1) * 4 + ks) * 32 + ((lane >> 4) << 3) + e;
    pw3[idx] = (_Float16)w3[n * 512 + k];
    return;
  }
  idx -= 131072;
  if (idx < 4096) {             // L4
    const int e = idx & 7, lane = (idx >> 3) & 63, f = idx >> 9;
    const int n = lane & 15;
    const int k = f * 32 + ((lane >> 4) << 3) + e;
    pw4[idx] = (_Float16)((n < 10) ? w4[n * 256 + k] : 0.0f);
    return;
  }
}

// ---------------------------------------------------------------------------
// Fused 4-layer MLP. 512 thr = 8 waves, 128 rows/block, grid 512.
// 39 staged 16KB weight phases, double-buffered; LDS 64KB -> 2 blocks/CU
// (4 waves/SIMD). Per-wave 4KB XOR-swizzled transpose buffer (wave-
// synchronous, no block barriers). x fragments prefetched one phase ahead.
// ---------------------------------------------------------------------------
__global__ __launch_bounds__(512, 4)
void fused_mlp(const float* __restrict__ x,
               const _Float16* __restrict__ pw1, const _Float16* __restrict__ pw2,
               const _Float16* __restrict__ pw3, const _Float16* __restrict__ pw4,
               const float* __restrict__ b1, const float* __restrict__ b2,
               const float* __restrict__ b3, const float* __restrict__ b4,
               float* __restrict__ out)
{
  __shared__ char wbuf[2][16384];
  __shared__ char tbuf[8][4096];   // per-wave [16 rows][256 B], XOR-swizzled

  const int tid  = (int)threadIdx.x;
  const int lane = tid & 63;
  const int wid  = tid >> 6;
  const int ln   = lane & 15;
  const int hi   = lane >> 4;
  const int rowBase = (int)blockIdx.x * 128 + wid * 16;
  char* tb = tbuf[wid];

  // phases 0..13: L1. 14+6g+r, r=0..1: L2(g), r=2..5: L3(g, half r>>1 &1...).
  // phase 38: L4 (8KB).
  auto stage = [&](int p) {
    const char* src; int rounds = 2;
    if (p < 14)      src = (const char*)pw1 + (size_t)p * 16384;
    else if (p < 38) {
      const int j = p - 14, g = j / 6, r = j - g * 6;
      src = (r < 2) ? (const char*)pw2 + (size_t)(g * 32768 + r * 16384)
                    : (const char*)pw3 + (size_t)(g * 65536 + (r - 2) * 16384);
    } else { src = (const char*)pw4; rounds = 1; }
    char* dst = wbuf[p & 1];
    for (int r = 0; r < rounds; ++r)
      async_cp16(src + r * 8192 + (size_t)tid * 16, dst + r * 8192 + wid * 1024);
  };

  auto Bfrag = [&](const char* buf, int f) -> half8 {
    return *(const half8*)(buf + (((f << 6) + lane) << 4));
  };
  // 16 rows x 128 cols f16, row stride 256B, XOR-swizzle bits 4-6 by row&7
  auto twrite = [&](int row, int col, float v) {
    const int off = (row << 8) + ((col << 1) ^ ((row & 7) << 4));
    *(_Float16*)(tb + off) = (_Float16)v;
  };
  auto tread = [&](int ks) -> half8 {
    const int off = (ln << 8) + (((ks << 6) + (hi << 4)) ^ ((ln & 7) << 4));
    return *(const half8*)(tb + off);
  };

  const float* xrow = x + (size_t)(rowBase + ln) * 784;
  auto loadA = [&](int gks) -> half8 {
    half8 h;
    const int k0 = gks * 32 + hi * 8;
    if (k0 < 784) {
      const f32x4 v0 = *(const f32x4*)(xrow + k0);
      const f32x4 v1 = *(const f32x4*)(xrow + k0 + 4);
      #pragma unroll
      for (int e = 0; e < 4; ++e) { h[e] = (_Float16)v0[e]; h[4 + e] = (_Float16)v1[e]; }
    } else {
      #pragma unroll
      for (int e = 0; e < 8; ++e) h[e] = (_Float16)0.0f;
    }
    return h;
  };

  // ---- Layer 1: 14 phases, 2 ksteps each ----
  f32x4 acc1[8];
  #pragma unroll
  for (int nt = 0; nt < 8; ++nt) {
    const float bv = b1[nt * 16 + ln];
    f32x4 a = {bv, bv, bv, bv}; acc1[nt] = a;
  }

  stage(0);
  half8 ap0 = loadA(0), ap1 = loadA(1);
  __syncthreads();

  for (int p = 0; p < 14; ++p) {
    stage(p + 1);
    const half8 a0 = ap0, a1 = ap1;
    if (p < 13) { ap0 = loadA(2 * p + 2); ap1 = loadA(2 * p + 3); }
    const char* bw = wbuf[p & 1];
    #pragma unroll
    for (int nt = 0; nt < 8; ++nt)
      acc1[nt] = __builtin_amdgcn_mfma_f32_16x16x32_f16(a0, Bfrag(bw, nt), acc1[nt], 0, 0, 0);
    #pragma unroll
    for (int nt = 0; nt < 8; ++nt)
      acc1[nt] = __builtin_amdgcn_mfma_f32_16x16x32_f16(a1, Bfrag(bw, 8 + nt), acc1[nt], 0, 0, 0);
    __syncthreads();
  }

  // h1 -> A-fragments (wave-synchronous LDS transpose)
  half8 a1h[4];
  #pragma unroll
  for (int nt = 0; nt < 8; ++nt)
    #pragma unroll
    for (int r = 0; r < 4; ++r)
      twrite(hi * 4 + r, nt * 16 + ln, fmaxf(acc1[nt][r], 0.0f));
  #pragma unroll
  for (int ks = 0; ks < 4; ++ks) a1h[ks] = tread(ks);

  f32x4 acc3[16];
  #pragma unroll
  for (int q = 0; q < 16; ++q) {
    const float bv = b3[q * 16 + ln];
    f32x4 a = {bv, bv, bv, bv}; acc3[q] = a;
  }

  // ---- Layers 2+3 interleaved, per 128-col chunk g of h2 (6 phases each) ----
  for (int g = 0; g < 4; ++g) {
    const int pb = 14 + 6 * g;   // even
    half8 a2c[4];
    f32x4 acc2[8];
    #pragma unroll
    for (int nt = 0; nt < 8; ++nt) {
      const float bv = b2[g * 128 + nt * 16 + ln];
      f32x4 a = {bv, bv, bv, bv}; acc2[nt] = a;
    }

    // L2 chunk 0 (ks 0,1) — buf even
    stage(pb + 1);
    {
      const char* bw = wbuf[0];
      #pragma unroll
      for (int nt = 0; nt < 8; ++nt)
        acc2[nt] = __builtin_amdgcn_mfma_f32_16x16x32_f16(a1h[0], Bfrag(bw, nt), acc2[nt], 0, 0, 0);
      #pragma unroll
      for (int nt = 0; nt < 8; ++nt)
        acc2[nt] = __builtin_amdgcn_mfma_f32_16x16x32_f16(a1h[1], Bfrag(bw, 8 + nt), acc2[nt], 0, 0, 0);
    }
    __syncthreads();

    // L2 chunk 1 (ks 2,3) — buf odd; then transpose h2 chunk -> a2c
    stage(pb + 2);
    {
      const char* bw = wbuf[1];
      #pragma unroll
      for (int nt = 0; nt < 8; ++nt)
        acc2[nt] = __builtin_amdgcn_mfma_f32_16x16x32_f16(a1h[2], Bfrag(bw, nt), acc2[nt], 0, 0, 0);
      #pragma unroll
      for (int nt = 0; nt < 8; ++nt)
        acc2[nt] = __builtin_amdgcn_mfma_f32_16x16x32_f16(a1h[3], Bfrag(bw, 8 + nt), acc2[nt], 0, 0, 0);
      #pragma unroll
      for (int nt = 0; nt < 8; ++nt)
        #pragma unroll
        for (int r = 0; r < 4; ++r)
          twrite(hi * 4 + r, nt * 16 + ln, fmaxf(acc2[nt][r], 0.0f));
      #pragma unroll
      for (int ks = 0; ks < 4; ++ks) a2c[ks] = tread(ks);
    }
    __syncthreads();

    // L3 half 0, ks 0,1 — buf even
    stage(pb + 3);
    {
      const char* bw = wbuf[0];
      #pragma unroll
      for (int nt = 0; nt < 8; ++nt)
        acc3[nt] = __builtin_amdgcn_mfma_f32_16x16x32_f16(a2c[0], Bfrag(bw, nt), acc3[nt], 0, 0, 0);
      #pragma unroll
      for (int nt = 0; nt < 8; ++nt)
        acc3[nt] = __builtin_amdgcn_mfma_f32_16x16x32_f16(a2c[1], Bfrag(bw, 8 + nt), acc3[nt], 0, 0, 0);
    }
    __syncthreads();

    // L3 half 0, ks 2,3 — buf odd
    stage(pb + 4);
    {
      const char* bw = wbuf[1];
      #pragma unroll
      for (int nt = 0; nt < 8; ++nt)
        acc3[nt] = __builtin_amdgcn_mfma_f32_16x16x32_f16(a2c[2], Bfrag(bw, nt), acc3[nt], 0, 0, 0);
      #pragma unroll
      for (int nt = 0; nt < 8; ++nt)
        acc3[nt] = __builtin_amdgcn_mfma_f32_16x16x32_f16(a2c[3], Bfrag(bw, 8 + nt), acc3[nt], 0, 0, 0);
    }
    __syncthreads();

    // L3 half 1, ks 0,1 — buf even
    stage(pb + 5);
    {
      const char* bw = wbuf[0];
      #pragma unroll
      for (int nt = 0; nt < 8; ++nt)
        acc3[8 + nt] = __builtin_amdgcn_mfma_f32_16x16x32_f16(a2c[0], Bfrag(bw, nt), acc3[8 + nt], 0, 0, 0);
      #pragma unroll
      for (int nt = 0; nt < 8; ++nt)
        acc3[8 + nt] = __builtin_amdgcn_mfma_f32_16x16x32_f16(a2c[1], Bfrag(bw, 8 + nt), acc3[8 + nt], 0, 0, 0);
    }
    __syncthreads();

    // L3 half 1, ks 2,3 — buf odd
    stage(pb + 6);
    {
      const char* bw = wbuf[1];
      #pragma unroll
      for (int nt = 0; nt < 8; ++nt)
        acc3[8 + nt] = __builtin_amdgcn_mfma_f32_16x16x32_f16(a2c[2], Bfrag(bw, nt), acc3[8 + nt], 0, 0, 0);
      #pragma unroll
      for (int nt = 0; nt < 8; ++nt)
        acc3[8 + nt] = __builtin_amdgcn_mfma_f32_16x16x32_f16(a2c[3], Bfrag(bw, 8 + nt), acc3[8 + nt], 0, 0, 0);
    }
    __syncthreads();
  }

  // ---- Layer 4 (phase 38, buf even) ----
  {
    half8 a3h[8];
    // h3 cols 0..127
    #pragma unroll
    for (int q = 0; q < 8; ++q)
      #pragma unroll
      for (int r = 0; r < 4; ++r)
        twrite(hi * 4 + r, q * 16 + ln, fmaxf(acc3[q][r], 0.0f));
    #pragma unroll
    for (int ks = 0; ks < 4; ++ks) a3h[ks] = tread(ks);
    // h3 cols 128..255
    #pragma unroll
    for (int q = 0; q < 8; ++q)
      #pragma unroll
      for (int r = 0; r < 4; ++r)
        twrite(hi * 4 + r, q * 16 + ln, fmaxf(acc3[8 + q][r], 0.0f));
    #pragma unroll
    for (int ks = 0; ks < 4; ++ks) a3h[4 + ks] = tread(ks);

    const float bv = (ln < 10) ? b4[ln] : 0.0f;
    f32x4 acc4 = {bv, bv, bv, bv};
    const char* bw = wbuf[0];
    #pragma unroll
    for (int ks = 0; ks < 8; ++ks)
      acc4 = __builtin_amdgcn_mfma_f32_16x16x32_f16(a3h[ks], Bfrag(bw, ks), acc4, 0, 0, 0);

    if (ln < 10) {
      #pragma unroll
      for (int r = 0; r < 4; ++r)
        out[(size_t)(rowBase + hi * 4 + r) * 10 + ln] = acc4[r];
    }
  }
}

// ---------------------------------------------------------------------------

extern "C" void kernel_launch(void* const* d_in, const int* in_sizes, int n_in,
                              void* d_out, int out_size, void* d_ws, size_t ws_size,
                              hipStream_t stream)
{
  const float* x     = (const float*)d_in[0];
  const float* wconv = (const float*)d_in[1];
  const float* w1    = (const float*)d_in[2];
  const float* b1    = (const float*)d_in[3];
  const float* w2    = (const float*)d_in[4];
  const float* b2    = (const float*)d_in[5];
  const float* w3    = (const float*)d_in[6];
  const float* b3    = (const float*)d_in[7];
  const float* w4    = (const float*)d_in[8];
  const float* b4    = (const float*)d_in[9];
  float* out = (float*)d_out;
  char*  ws  = (char*)d_ws;

  _Float16* pw1 = (_Float16*)(ws + 0);        // 114688 f16 = 229376 B
  _Float16* pw2 = (_Float16*)(ws + 229376);   //  65536 f16 = 131072 B
  _Float16* pw3 = (_Float16*)(ws + 360448);   // 131072 f16 = 262144 B
  _Float16* pw4 = (_Float16*)(ws + 622592);   //   4096 f16 =   8192 B

  pack_all<<<1232, 256, 0, stream>>>(w1, wconv, w2, w3, w4, pw1, pw2, pw3, pw4);
  fused_mlp<<<512, 512, 0, stream>>>(x, pw1, pw2, pw3, pw4, b1, b2, b3, b4, out);
}

// Round 4
// 364.417 us; speedup vs baseline: 1.1389x; 1.1389x over previous
//
#include <hip/hip_runtime.h>
#include <stdint.h>

typedef _Float16 half8  __attribute__((ext_vector_type(8)));
typedef float    f32x4  __attribute__((ext_vector_type(4)));
typedef float    f32x16 __attribute__((ext_vector_type(16)));

static __device__ __forceinline__ void async_cp16(const void* g, void* l) {
  __builtin_amdgcn_global_load_lds(
      (const __attribute__((address_space(1))) uint32_t*)g,
      (__attribute__((address_space(3))) uint32_t*)l,
      16, 0, 0);
}

// ---------------------------------------------------------------------------
// Weight packing into 32x32x16 MFMA B-fragment order.
// Fragment (1 KB): lane -> n = nbase + (lane&31), k = kbase + (lane>>5)*8 + e.
// pw1: 7 chunks x 28 frags (f=ks_in*4+nt), ks=c*7+ks_in (49 total, K=784 exact),
//      n=nt*32+..., conv folded.                         100352 elems
// pw2: 4 chunks (g) x 32 frags (f=ks_in*4+nt), n=g*128+nt*32+..., K=128.  65536
// pw3: 8 chunks (cc=g*2+h) x 32 frags (f=ks_in*8+nt), n=nt*32+...,
//      k=(cc*4+ks_in)*16+...                                             131072
// pw4: 16 frags (f=ks), n=lane&31 (<10 real), k=f*16+...                   8192
// ---------------------------------------------------------------------------
__global__ void pack_all(const float* __restrict__ w1, const float* __restrict__ wc,
                         const float* __restrict__ w2, const float* __restrict__ w3,
                         const float* __restrict__ w4,
                         _Float16* __restrict__ pw1, _Float16* __restrict__ pw2,
                         _Float16* __restrict__ pw3, _Float16* __restrict__ pw4)
{
  int idx = (int)blockIdx.x * 256 + (int)threadIdx.x;

  if (idx < 100352) {           // L1 (conv folded)
    const int e = idx & 7, lane = (idx >> 3) & 63, t = idx >> 9;
    const int c = t / 28, fl = t - c * 28;
    const int ks_in = fl >> 2, nt = fl & 3;
    const int n = nt * 32 + (lane & 31);
    const int k = (c * 7 + ks_in) * 16 + ((lane >> 5) << 3) + e;   // < 784
    float val = 0.0f;
    {
      const int pr = k / 28, pc = k % 28;
      #pragma unroll
      for (int i = 0; i < 3; ++i)
        #pragma unroll
        for (int j = 0; j < 3; ++j) {
          const int orow = pr - i, ocol = pc - j;
          if (orow >= 0 && orow < 26 && ocol >= 0 && ocol < 26)
            val += wc[i * 3 + j] * w1[n * 676 + orow * 26 + ocol];
        }
    }
    pw1[idx] = (_Float16)val;
    return;
  }
  idx -= 100352;
  if (idx < 65536) {            // L2
    const int e = idx & 7, lane = (idx >> 3) & 63, t = idx >> 9;
    const int g = t >> 5, fl = t & 31;
    const int ks_in = fl >> 2, nt = fl & 3;
    const int n = g * 128 + nt * 32 + (lane & 31);
    const int k = ks_in * 16 + ((lane >> 5) << 3) + e;
    pw2[idx] = (_Float16)w2[n * 128 + k];
    return;
  }
  idx -= 65536;
  if (idx < 131072) {           // L3
    const int e = idx & 7, lane = (idx >> 3) & 63, t = idx >> 9;
    const int cc = t >> 5, fl = t & 31;
    const int ks_in = fl >> 3, nt = fl & 7;
    const int n = nt * 32 + (lane & 31);
    const int k = (cc * 4 + ks_in) * 16 + ((lane >> 5) << 3) + e;
    pw3[idx] = (_Float16)w3[n * 512 + k];
    return;
  }
  idx -= 131072;
  if (idx < 8192) {             // L4
    const int e = idx & 7, lane = (idx >> 3) & 63, t = idx >> 9;
    const int n = lane & 31;
    const int k = t * 16 + ((lane >> 5) << 3) + e;
    pw4[idx] = (_Float16)((n < 10) ? w4[n * 256 + k] : 0.0f);
    return;
  }
}

// ---------------------------------------------------------------------------
// Fused 4-layer MLP, 32x32x16 MFMA. 512 thr = 8 waves = 2 row-groups x 4
// N-slices; 64 rows/block; grid 1024. 20 staged weight phases (<=32 KB),
// double-buffered. LDS 80 KB -> 2 blocks/CU. One 16-KB XOR-swizzled tbuf
// for all layer transposes; h1 A-frags held in registers across all chunks.
// ---------------------------------------------------------------------------
__global__ __launch_bounds__(512, 4)
void fused_mlp(const float* __restrict__ x,
               const _Float16* __restrict__ pw1, const _Float16* __restrict__ pw2,
               const _Float16* __restrict__ pw3, const _Float16* __restrict__ pw4,
               const float* __restrict__ b1, const float* __restrict__ b2,
               const float* __restrict__ b3, const float* __restrict__ b4,
               float* __restrict__ out)
{
  __shared__ char wbuf[2][32768];
  __shared__ char tbuf[16384];   // 64 rows x 256 B (128 f16 cols), XOR-swizzled

  const int tid  = (int)threadIdx.x;
  const int lane = tid & 63;
  const int wid  = tid >> 6;
  const int l31  = lane & 31;
  const int lh   = lane >> 5;          // 0/1
  const int rg   = wid >> 2;           // row-group 0/1 (32 rows each)
  const int nq   = wid & 3;            // N-slice 0..3
  const int rowBase = (int)blockIdx.x * 64 + rg * 32;

  // phases: 0..6 L1 | 7+3g: L2(g), L3a(g), L3b(g) | 19: L4
  auto stage = [&](int p) {
    const char* src; int nb;
    if (p < 7)       { src = (const char*)pw1 + (size_t)p * 28672; nb = 28672; }
    else if (p < 19) {
      const int j = p - 7, g = j / 3, r = j - g * 3;
      if (r == 0) { src = (const char*)pw2 + (size_t)g * 32768; nb = 32768; }
      else        { src = (const char*)pw3 + (size_t)g * 65536 + (size_t)(r - 1) * 32768; nb = 32768; }
    } else           { src = (const char*)pw4; nb = 16384; }
    char* dst = wbuf[p & 1];
    for (int off = tid * 16; off < nb; off += 8192)   // wave-uniform trip count
      async_cp16(src + off, dst + off);
  };

  auto Bfrag = [&](const char* buf, int f) -> half8 {
    return *(const half8*)(buf + (f << 10) + (lane << 4));
  };
  // transpose store: (row_local 0..31, col 0..127) f16, swizzle bits 4-6 by row&7
  auto twr = [&](int r32, int c, float v) {
    *(_Float16*)(tbuf + ((rg * 32 + r32) << 8) + ((c * 2) ^ ((r32 & 7) << 4))) = (_Float16)v;
  };
  // A-frag read: row = l31 (of this rg), k = ks*16 + lh*8 .. +8
  auto trd = [&](int ks) -> half8 {
    const int koff = (ks * 16 + lh * 8) * 2;
    return *(const half8*)(tbuf + ((rg * 32 + l31) << 8) + (koff ^ ((l31 & 7) << 4)));
  };

  const float* xrow = x + (size_t)(rowBase + l31) * 784;
  auto loadA = [&](int gks) -> half8 {   // gks in [0,49): k0+8 <= 784 always
    const int k0 = gks * 16 + lh * 8;
    const f32x4 v0 = *(const f32x4*)(xrow + k0);
    const f32x4 v1 = *(const f32x4*)(xrow + k0 + 4);
    half8 h;
    #pragma unroll
    for (int e = 0; e < 4; ++e) { h[e] = (_Float16)v0[e]; h[4 + e] = (_Float16)v1[e]; }
    return h;
  };

  // ---- Layer 1: 7 phases x 7 ksteps, rows rg*32, cols nq*32 ----
  f32x16 acc1;
  {
    const float bv = b1[nq * 32 + l31];
    #pragma unroll
    for (int r = 0; r < 16; ++r) acc1[r] = bv;
  }

  stage(0);
  half8 ap[7];
  #pragma unroll
  for (int i = 0; i < 7; ++i) ap[i] = loadA(i);
  __syncthreads();

  #pragma unroll
  for (int p = 0; p < 7; ++p) {
    stage(p + 1);
    half8 ac[7];
    #pragma unroll
    for (int i = 0; i < 7; ++i) ac[i] = ap[i];
    if (p < 6) {
      #pragma unroll
      for (int i = 0; i < 7; ++i) ap[i] = loadA((p + 1) * 7 + i);
    }
    const char* bw = wbuf[p & 1];
    #pragma unroll
    for (int i = 0; i < 7; ++i)
      acc1 = __builtin_amdgcn_mfma_f32_32x32x16_f16(ac[i], Bfrag(bw, i * 4 + nq), acc1, 0, 0, 0);
    if (p == 6) {
      #pragma unroll
      for (int r = 0; r < 16; ++r) {
        const int r32 = (r & 3) + 8 * (r >> 2) + 4 * lh;
        twr(r32, nq * 32 + l31, fmaxf(acc1[r], 0.0f));
      }
    }
    __syncthreads();
  }

  // ---- Layers 2+3, per 128-col h2 chunk g ----
  half8 a1h[8];
  f32x16 acc3[2];
  {
    const float bva = b3[nq * 64 + l31], bvb = b3[nq * 64 + 32 + l31];
    #pragma unroll
    for (int r = 0; r < 16; ++r) { acc3[0][r] = bva; acc3[1][r] = bvb; }
  }

  #pragma unroll
  for (int g = 0; g < 4; ++g) {
    const int p = 7 + 3 * g;

    // L2(g): acc2 = h1 @ W2[:, g-chunk], wave owns 32 cols
    stage(p + 1);
    if (g == 0) {
      #pragma unroll
      for (int ks = 0; ks < 8; ++ks) a1h[ks] = trd(ks);   // h1 A-frags, K=128
    }
    f32x16 acc2;
    {
      const float bv = b2[g * 128 + nq * 32 + l31];
      #pragma unroll
      for (int r = 0; r < 16; ++r) acc2[r] = bv;
    }
    {
      const char* bw = wbuf[p & 1];
      #pragma unroll
      for (int ks = 0; ks < 8; ++ks)
        acc2 = __builtin_amdgcn_mfma_f32_32x32x16_f16(a1h[ks], Bfrag(bw, ks * 4 + nq), acc2, 0, 0, 0);
    }
    __syncthreads();   // all tbuf readers (a1h at g=0 / prev a2c) done
    #pragma unroll
    for (int r = 0; r < 16; ++r) {
      const int r32 = (r & 3) + 8 * (r >> 2) + 4 * lh;
      twr(r32, nq * 32 + l31, fmaxf(acc2[r], 0.0f));
    }
    __syncthreads();   // h2 chunk visible; stage(p+1) drained

    // L3a: K-slice ks 0..3 of chunk
    {
      stage(p + 2);
      half8 a2c[4];
      #pragma unroll
      for (int ks = 0; ks < 4; ++ks) a2c[ks] = trd(ks);
      const char* bw = wbuf[(p + 1) & 1];
      #pragma unroll
      for (int ks = 0; ks < 4; ++ks)
        #pragma unroll
        for (int t = 0; t < 2; ++t)
          acc3[t] = __builtin_amdgcn_mfma_f32_32x32x16_f16(
              a2c[ks], Bfrag(bw, ks * 8 + nq * 2 + t), acc3[t], 0, 0, 0);
      __syncthreads();
    }
    // L3b: K-slice ks 4..7
    {
      stage(p + 3);
      half8 a2c[4];
      #pragma unroll
      for (int ks = 0; ks < 4; ++ks) a2c[ks] = trd(4 + ks);
      const char* bw = wbuf[(p + 2) & 1];
      #pragma unroll
      for (int ks = 0; ks < 4; ++ks)
        #pragma unroll
        for (int t = 0; t < 2; ++t)
          acc3[t] = __builtin_amdgcn_mfma_f32_32x32x16_f16(
              a2c[ks], Bfrag(bw, ks * 8 + nq * 2 + t), acc3[t], 0, 0, 0);
      __syncthreads();
    }
  }

  // ---- Layer 4 (phase 19, wbuf[1]): two K-half passes through tbuf ----
  {
    const char* bw = wbuf[1];
    f32x16 acc4;
    {
      const float bv = (l31 < 10) ? b4[l31] : 0.0f;
      #pragma unroll
      for (int r = 0; r < 16; ++r) acc4[r] = bv;
    }
    // pass 0: h3 cols 0..127 (waves nq 0,1)
    if (nq < 2) {
      #pragma unroll
      for (int t = 0; t < 2; ++t)
        #pragma unroll
        for (int r = 0; r < 16; ++r) {
          const int r32 = (r & 3) + 8 * (r >> 2) + 4 * lh;
          twr(r32, nq * 64 + t * 32 + l31, fmaxf(acc3[t][r], 0.0f));
        }
    }
    __syncthreads();
    #pragma unroll
    for (int ks = 0; ks < 8; ++ks)
      acc4 = __builtin_amdgcn_mfma_f32_32x32x16_f16(trd(ks), Bfrag(bw, ks), acc4, 0, 0, 0);
    __syncthreads();
    // pass 1: h3 cols 128..255 (waves nq 2,3)
    if (nq >= 2) {
      #pragma unroll
      for (int t = 0; t < 2; ++t)
        #pragma unroll
        for (int r = 0; r < 16; ++r) {
          const int r32 = (r & 3) + 8 * (r >> 2) + 4 * lh;
          twr(r32, (nq - 2) * 64 + t * 32 + l31, fmaxf(acc3[t][r], 0.0f));
        }
    }
    __syncthreads();
    #pragma unroll
    for (int ks = 0; ks < 8; ++ks)
      acc4 = __builtin_amdgcn_mfma_f32_32x32x16_f16(trd(ks), Bfrag(bw, 8 + ks), acc4, 0, 0, 0);

    if (nq == 0) {
      #pragma unroll
      for (int r = 0; r < 16; ++r) {
        const int r32 = (r & 3) + 8 * (r >> 2) + 4 * lh;
        if (l31 < 10)
          out[(size_t)(rowBase + r32) * 10 + l31] = acc4[r];
      }
    }
  }
}

// ---------------------------------------------------------------------------

extern "C" void kernel_launch(void* const* d_in, const int* in_sizes, int n_in,
                              void* d_out, int out_size, void* d_ws, size_t ws_size,
                              hipStream_t stream)
{
  const float* x     = (const float*)d_in[0];
  const float* wconv = (const float*)d_in[1];
  const float* w1    = (const float*)d_in[2];
  const float* b1    = (const float*)d_in[3];
  const float* w2    = (const float*)d_in[4];
  const float* b2    = (const float*)d_in[5];
  const float* w3    = (const float*)d_in[6];
  const float* b3    = (const float*)d_in[7];
  const float* w4    = (const float*)d_in[8];
  const float* b4    = (const float*)d_in[9];
  float* out = (float*)d_out;
  char*  ws  = (char*)d_ws;

  _Float16* pw1 = (_Float16*)(ws + 0);        // 100352 f16 = 200704 B
  _Float16* pw2 = (_Float16*)(ws + 200704);   //  65536 f16 = 131072 B
  _Float16* pw3 = (_Float16*)(ws + 331776);   // 131072 f16 = 262144 B
  _Float16* pw4 = (_Float16*)(ws + 593920);   //   8192 f16 =  16384 B

  pack_all<<<1192, 256, 0, stream>>>(w1, wconv, w2, w3, w4, pw1, pw2, pw3, pw4);
  fused_mlp<<<1024, 512, 0, stream>>>(x, pw1, pw2, pw3, pw4, b1, b2, b3, b4, out);
}